// Round 8
// baseline (85.539 us; speedup 1.0000x reference)
//
#include <hip/hip_runtime.h>

#define T_FRAMES 256
#define D_IN 80
#define CCH 256
#define CCEP 222
#define FFT_N 1024
#define HOP 256
#define WINL 512
#define PF_KT 128
#define ZLEN 65536

__device__ __forceinline__ unsigned br10(unsigned x) { return __brev(x) >> 22; }

// ---- K0: weight transpose (Cout, Cin*K) -> (Cin*K, Cout) ----
__global__ void transpose_k(const float* __restrict__ w1, const float* __restrict__ w2,
                            const float* __restrict__ w3,
                            float* __restrict__ w1t, float* __restrict__ w2t, float* __restrict__ w3t) {
  int tid = blockIdx.x * blockDim.x + threadIdx.x;
  int stride = gridDim.x * blockDim.x;
  for (int idx = tid; idx < 240 * 256; idx += stride) { int i = idx >> 8, c = idx & 255; w1t[idx] = w1[c * 240 + i]; }
  for (int idx = tid; idx < 768 * 256; idx += stride) { int i = idx >> 8, c = idx & 255; w2t[idx] = w2[c * 768 + i]; }
  for (int idx = tid; idx < 768 * CCEP; idx += stride) { int i = idx / CCEP, c = idx - i * CCEP; w3t[idx] = w3[c * 768 + i]; }
}

// ---- K1: conv1 (T,80)->(T,256) K=3 relu. 64 blocks x 4 frames; thread=c.
//      inputs: wave-uniform float4 broadcast from global; weights coalesced from w1t ----
__global__ __launch_bounds__(256) void conv1_k(const float* __restrict__ x, const float* __restrict__ w1t,
                                               const float* __restrict__ b1, float* __restrict__ h1) {
  const int t0 = blockIdx.x * 4, c = threadIdx.x;
  const float4* x4 = (const float4*)x;  // [t][20]
  float bb = b1[c];
  float a0 = bb, a1 = bb, a2 = bb, a3 = bb;
  for (int cg = 0; cg < 20; ++cg) {
    float4 xr[6];
    #pragma unroll
    for (int r = 0; r < 6; ++r) {
      int tt = t0 - 1 + r;
      xr[r] = (tt >= 0 && tt < T_FRAMES) ? x4[tt * 20 + cg] : make_float4(0.f, 0.f, 0.f, 0.f);
    }
    #pragma unroll
    for (int ci = 0; ci < 4; ++ci) {
      int cin = cg * 4 + ci;
      #pragma unroll
      for (int k = 0; k < 3; ++k) {
        float w = w1t[(cin * 3 + k) * 256 + c];
        a0 += ((const float*)&xr[k + 0])[ci] * w;
        a1 += ((const float*)&xr[k + 1])[ci] * w;
        a2 += ((const float*)&xr[k + 2])[ci] * w;
        a3 += ((const float*)&xr[k + 3])[ci] * w;
      }
    }
  }
  h1[(t0 + 0) * CCH + c] = fmaxf(a0, 0.f);
  h1[(t0 + 1) * CCH + c] = fmaxf(a1, 0.f);
  h1[(t0 + 2) * CCH + c] = fmaxf(a2, 0.f);
  h1[(t0 + 3) * CCH + c] = fmaxf(a3, 0.f);
}

// ---- K2: conv2 split-K x4, partials. block (g=b>>2, kc=b&3); thread=c. ----
__global__ __launch_bounds__(256) void conv2_k(const float* __restrict__ h1, const float* __restrict__ w2t,
                                               float* __restrict__ h2p) {
  const int b = blockIdx.x, c = threadIdx.x;
  const int g = b >> 2, kc = b & 3, t0 = g << 2;
  const int cbase = kc << 6, cb4 = kc << 4;
  const float4* h14 = (const float4*)h1;  // [t][64]
  float a0 = 0.f, a1 = 0.f, a2 = 0.f, a3 = 0.f;
  for (int cg = 0; cg < 16; ++cg) {
    float4 hr[6];
    #pragma unroll
    for (int r = 0; r < 6; ++r) {
      int tt = t0 - 1 + r;
      hr[r] = (tt >= 0 && tt < T_FRAMES) ? h14[tt * 64 + cb4 + cg] : make_float4(0.f, 0.f, 0.f, 0.f);
    }
    #pragma unroll
    for (int ci = 0; ci < 4; ++ci) {
      int cin = cbase + cg * 4 + ci;
      #pragma unroll
      for (int k = 0; k < 3; ++k) {
        float w = w2t[(cin * 3 + k) * 256 + c];
        a0 += ((const float*)&hr[k + 0])[ci] * w;
        a1 += ((const float*)&hr[k + 1])[ci] * w;
        a2 += ((const float*)&hr[k + 2])[ci] * w;
        a3 += ((const float*)&hr[k + 3])[ci] * w;
      }
    }
  }
  const int ob = kc << 8;
  h2p[(ob + t0 + 0) * CCH + c] = a0;
  h2p[(ob + t0 + 1) * CCH + c] = a1;
  h2p[(ob + t0 + 2) * CCH + c] = a2;
  h2p[(ob + t0 + 3) * CCH + c] = a3;
}

// ---- K3: conv3 split-K x4 (sums conv2 partials + bias2 + relu inline) ----
__global__ __launch_bounds__(256) void conv3_k(const float* __restrict__ h2p, const float* __restrict__ w3t,
                                               const float* __restrict__ b2, float* __restrict__ ccp) {
  const int b = blockIdx.x, c = threadIdx.x;
  const int g = b >> 2, kc = b & 3, t0 = g << 2;
  const int cbase = kc << 6, cb4 = kc << 4;
  const float4* h2p4 = (const float4*)h2p;  // [p*256+t][64]
  const float4* b24 = (const float4*)b2;    // [64]
  float a0 = 0.f, a1 = 0.f, a2 = 0.f, a3 = 0.f;
  for (int cg = 0; cg < 16; ++cg) {
    float4 hr[6];
    #pragma unroll
    for (int r = 0; r < 6; ++r) {
      int tt = t0 - 1 + r;
      if (tt >= 0 && tt < T_FRAMES) {
        float4 s = b24[cb4 + cg];
        #pragma unroll
        for (int p = 0; p < 4; ++p) {
          float4 v = h2p4[((p << 8) + tt) * 64 + cb4 + cg];
          s.x += v.x; s.y += v.y; s.z += v.z; s.w += v.w;
        }
        s.x = fmaxf(s.x, 0.f); s.y = fmaxf(s.y, 0.f); s.z = fmaxf(s.z, 0.f); s.w = fmaxf(s.w, 0.f);
        hr[r] = s;
      } else {
        hr[r] = make_float4(0.f, 0.f, 0.f, 0.f);
      }
    }
    if (c < CCEP) {
      #pragma unroll
      for (int ci = 0; ci < 4; ++ci) {
        int cin = cbase + cg * 4 + ci;
        #pragma unroll
        for (int k = 0; k < 3; ++k) {
          float w = w3t[(cin * 3 + k) * CCEP + c];
          a0 += ((const float*)&hr[k + 0])[ci] * w;
          a1 += ((const float*)&hr[k + 1])[ci] * w;
          a2 += ((const float*)&hr[k + 2])[ci] * w;
          a3 += ((const float*)&hr[k + 3])[ci] * w;
        }
      }
    }
  }
  if (c < CCEP) {
    const int ob = kc << 8;
    ccp[(ob + t0 + 0) * CCEP + c] = a0;
    ccp[(ob + t0 + 1) * CCEP + c] = a1;
    ccp[(ob + t0 + 2) * CCEP + c] = a2;
    ccp[(ob + t0 + 3) * CCEP + c] = a3;
  }
}

// ---- K4: fused spectral kernel (correlation theorem, one fwd + one inv FFT) ----
__global__ __launch_bounds__(512) void fftltv_k(const float* __restrict__ ccp, const float* __restrict__ b3,
                                                const float* __restrict__ quef, const float* __restrict__ z,
                                                const float* __restrict__ win, float* __restrict__ outw) {
  __shared__ float2 U[FFT_N];
  int t = blockIdx.x, tid = threadIdx.x;
  for (int i = tid; i < FFT_N; i += 512) {
    unsigned q = br10((unsigned)i);
    float a = 0.f, bv = 0.f;
    if (q >= 401u && q < 623u) {
      int cq = (int)(q - 401u);
      int base = t * CCEP + cq;
      a = (b3[cq] + ccp[base] + ccp[256 * CCEP + base] + ccp[512 * CCEP + base] + ccp[768 * CCEP + base]) / quef[cq];
    }
    if (q < 512u) {
      int idx = t * HOP + (int)q - 255;
      bv = (idx >= 0 && idx < ZLEN) ? z[idx] : 0.f;
    }
    U[i] = make_float2(a, bv);
  }
  __syncthreads();
  #pragma unroll
  for (int s = 1; s <= 10; ++s) {
    int half = 1 << (s - 1);
    int pos = tid & (half - 1);
    int i1 = ((tid >> (s - 1)) << s) + pos;
    int i2 = i1 + half;
    float ang = (-6.283185307179586f / (float)(1 << s)) * (float)pos;
    float sn, cs; __sincosf(ang, &sn, &cs);
    float2 v2 = U[i2], v1 = U[i1];
    float tr = cs * v2.x - sn * v2.y;
    float ti = cs * v2.y + sn * v2.x;
    U[i1] = make_float2(v1.x + tr, v1.y + ti);
    U[i2] = make_float2(v1.x - tr, v1.y - ti);
    __syncthreads();
  }
  {
    int j = tid;
    int mj = (FFT_N - j) & (FFT_N - 1);
    float2 Uj = U[j], Um = U[mj];
    float2 U5j = make_float2(0.f, 0.f);
    if (tid == 0) U5j = U[512];
    auto pcalc = [](float2 Uj, float2 Um) -> float2 {
      float Ar = 0.5f * (Uj.x + Um.x);
      float Ai = 0.5f * (Uj.y - Um.y);
      float Bx = 0.5f * (Uj.y + Um.y);
      float By = 0.5f * (Um.x - Uj.x);
      float mag = __expf(0.23025850929940457f * Ar);
      float sn, cs; __sincosf(Ai, &sn, &cs);
      float SPx = mag * cs, SPy = mag * sn;
      return make_float2(Bx * SPx + By * SPy, Bx * SPy - By * SPx);
    };
    float2 Pj = pcalc(Uj, Um);
    float2 P5 = (tid == 0) ? pcalc(U5j, U5j) : make_float2(0.f, 0.f);
    __syncthreads();
    U[j] = Pj;
    if (tid == 0) U[512] = P5;
    else U[mj] = make_float2(Pj.x, -Pj.y);
  }
  __syncthreads();
  #pragma unroll
  for (int s = 10; s >= 1; --s) {
    int half = 1 << (s - 1);
    int pos = tid & (half - 1);
    int i1 = ((tid >> (s - 1)) << s) + pos;
    int i2 = i1 + half;
    float ang = (6.283185307179586f / (float)(1 << s)) * (float)pos;
    float sn, cs; __sincosf(ang, &sn, &cs);
    float2 v1 = U[i1], v2 = U[i2];
    U[i1] = make_float2(v1.x + v2.x, v1.y + v2.y);
    float dr = v1.x - v2.x, di = v1.y - v2.y;
    U[i2] = make_float2(cs * dr - sn * di, cs * di + sn * dr);
    __syncthreads();
  }
  const float inv = 1.0f / (float)FFT_N;
  for (int i = tid; i < FFT_N; i += 512) {
    unsigned m = br10((unsigned)i);
    if (m < 512u) {
      int w = 511 - (int)m;
      outw[t * WINL + w] = U[i].x * inv * win[w];
    }
  }
}

// ---- K5: overlap-add (circular roll over t) + 128-tap postfilter ----
__global__ __launch_bounds__(256) void pf_k(const float* __restrict__ outw, const float* __restrict__ pf_w,
                                            const float* __restrict__ pf_b, float* __restrict__ y) {
  __shared__ float sb[256 + PF_KT - 1];
  __shared__ float wpf[PF_KT];
  int n0 = blockIdx.x * 256;
  for (int i = threadIdx.x; i < 256 + PF_KT - 1; i += 256) {
    int m = n0 - 63 + i;
    float v = 0.f;
    if (m >= 0 && m < ZLEN) {
      int t = m >> 8, j = m & 255;
      v = outw[t * WINL + j] + outw[((t - 1) & 255) * WINL + HOP + j];
    }
    sb[i] = v;
  }
  if (threadIdx.x < PF_KT) wpf[threadIdx.x] = pf_w[threadIdx.x];
  __syncthreads();
  float acc = pf_b[0];
  #pragma unroll 8
  for (int j = 0; j < PF_KT; ++j) acc += sb[threadIdx.x + j] * wpf[j];
  y[n0 + threadIdx.x] = acc;
}

extern "C" void kernel_launch(void* const* d_in, const int* in_sizes, int n_in,
                              void* d_out, int out_size, void* d_ws, size_t ws_size,
                              hipStream_t stream) {
  const float* x    = (const float*)d_in[0];
  const float* z    = (const float*)d_in[1];
  const float* w1   = (const float*)d_in[2];
  const float* b1   = (const float*)d_in[3];
  const float* w2   = (const float*)d_in[4];
  const float* b2   = (const float*)d_in[5];
  const float* w3   = (const float*)d_in[6];
  const float* b3   = (const float*)d_in[7];
  const float* pf_w = (const float*)d_in[8];
  const float* pf_b = (const float*)d_in[9];
  const float* quef = (const float*)d_in[10];
  const float* win  = (const float*)d_in[11];
  float* out = (float*)d_out;
  float* ws  = (float*)d_ws;

  // workspace layout (floats)
  float* w1t  = ws;                 // 240*256   = 61440
  float* w2t  = w1t + 61440;        // 768*256   = 196608
  float* w3t  = w2t + 196608;       // 768*222   = 170496
  float* h1   = w3t + 170496;       // 256*256   = 65536
  float* h2p  = h1 + 65536;         // 4*256*256 = 262144
  float* ccp  = h2p + 262144;       // 4*256*222 = 227328
  float* outw = ccp + 227328;       // 256*512   = 131072

  transpose_k<<<256, 256, 0, stream>>>(w1, w2, w3, w1t, w2t, w3t);
  conv1_k<<<64, 256, 0, stream>>>(x, w1t, b1, h1);
  conv2_k<<<256, 256, 0, stream>>>(h1, w2t, h2p);
  conv3_k<<<256, 256, 0, stream>>>(h2p, w3t, b2, ccp);
  fftltv_k<<<T_FRAMES, 512, 0, stream>>>(ccp, b3, quef, z, win, outw);
  pf_k<<<ZLEN / 256, 256, 0, stream>>>(outw, pf_w, pf_b, out);
}

// Round 9
// 48.674 us; speedup vs baseline: 1.7574x; 1.7574x over previous
//
#include <hip/hip_runtime.h>

#define T_FRAMES 256
#define D_IN 80
#define CCH 256
#define CCEP 222
#define FFT_N 1024
#define HOP 256
#define WINL 512
#define PF_KT 128
#define ZLEN 65536

__device__ __forceinline__ unsigned br10(unsigned x) { return __brev(x) >> 22; }

// ---- K0: weight transpose (Cout, Cin*K) -> (Cin*K, Cout) ----
__global__ void transpose_k(const float* __restrict__ w1, const float* __restrict__ w2,
                            const float* __restrict__ w3,
                            float* __restrict__ w1t, float* __restrict__ w2t, float* __restrict__ w3t) {
  int tid = blockIdx.x * blockDim.x + threadIdx.x;
  int stride = gridDim.x * blockDim.x;
  for (int idx = tid; idx < 240 * 256; idx += stride) { int i = idx >> 8, c = idx & 255; w1t[idx] = w1[c * 240 + i]; }
  for (int idx = tid; idx < 768 * 256; idx += stride) { int i = idx >> 8, c = idx & 255; w2t[idx] = w2[c * 768 + i]; }
  for (int idx = tid; idx < 768 * CCEP; idx += stride) { int i = idx / CCEP, c = idx - i * CCEP; w3t[idx] = w3[c * 768 + i]; }
}

// ---- K1: conv1. 128 blocks x 512 thr; thread-half f owns frame 2b+f; LDS b128 broadcast inputs ----
__global__ __launch_bounds__(512) void conv1_k(const float* __restrict__ x, const float* __restrict__ w1t,
                                               const float* __restrict__ b1, float* __restrict__ h1) {
  __shared__ float4 xs4[4 * 20];  // frames 2b-1 .. 2b+2, 80 floats each
  const int b = blockIdx.x, tid = threadIdx.x;
  const float4* x4 = (const float4*)x;
  if (tid < 80) {
    int r = tid / 20, cg = tid - r * 20;
    int tt = 2 * b - 1 + r;
    xs4[tid] = (tt >= 0 && tt < T_FRAMES) ? x4[tt * 20 + cg] : make_float4(0.f, 0.f, 0.f, 0.f);
  }
  __syncthreads();
  const int f = tid >> 8, c = tid & 255;
  const int t = 2 * b + f;
  float acc = b1[c];
  for (int cg = 0; cg < 20; ++cg) {
    float4 xr0 = xs4[(f + 0) * 20 + cg];
    float4 xr1 = xs4[(f + 1) * 20 + cg];
    float4 xr2 = xs4[(f + 2) * 20 + cg];
    #pragma unroll
    for (int ci = 0; ci < 4; ++ci) {
      int cin = cg * 4 + ci;
      float x0 = ((const float*)&xr0)[ci];
      float x1 = ((const float*)&xr1)[ci];
      float x2 = ((const float*)&xr2)[ci];
      acc += x0 * w1t[(cin * 3 + 0) * 256 + c];
      acc += x1 * w1t[(cin * 3 + 1) * 256 + c];
      acc += x2 * w1t[(cin * 3 + 2) * 256 + c];
    }
  }
  h1[t * CCH + c] = fmaxf(acc, 0.f);
}

// ---- K2: conv2 split-K x4 partials. 256 blocks x 512 thr; halves own frame-pairs ----
__global__ __launch_bounds__(512) void conv2_k(const float* __restrict__ h1, const float* __restrict__ w2t,
                                               float* __restrict__ h2p) {
  __shared__ float4 hs4[6 * 16];  // frames t0-1 .. t0+4, cin chunk of 64
  const int b = blockIdx.x, tid = threadIdx.x;
  const int g = b >> 2, kc = b & 3, t0 = g << 2;
  const float4* h14 = (const float4*)h1;  // [t][64]
  if (tid < 96) {
    int r = tid >> 4, cg = tid & 15;
    int tt = t0 - 1 + r;
    hs4[tid] = (tt >= 0 && tt < T_FRAMES) ? h14[tt * 64 + (kc << 4) + cg] : make_float4(0.f, 0.f, 0.f, 0.f);
  }
  __syncthreads();
  const int fb = (tid >> 8) << 1, c = tid & 255;  // frames t0+fb, t0+fb+1
  float a0 = 0.f, a1 = 0.f;
  for (int cg = 0; cg < 16; ++cg) {
    float4 hr0 = hs4[(fb + 0) * 16 + cg];
    float4 hr1 = hs4[(fb + 1) * 16 + cg];
    float4 hr2 = hs4[(fb + 2) * 16 + cg];
    float4 hr3 = hs4[(fb + 3) * 16 + cg];
    #pragma unroll
    for (int ci = 0; ci < 4; ++ci) {
      int cin = (kc << 6) + cg * 4 + ci;
      float h0 = ((const float*)&hr0)[ci];
      float h1v = ((const float*)&hr1)[ci];
      float h2v = ((const float*)&hr2)[ci];
      float h3 = ((const float*)&hr3)[ci];
      float wk0 = w2t[(cin * 3 + 0) * 256 + c];
      float wk1 = w2t[(cin * 3 + 1) * 256 + c];
      float wk2 = w2t[(cin * 3 + 2) * 256 + c];
      a0 += h0 * wk0 + h1v * wk1 + h2v * wk2;
      a1 += h1v * wk0 + h2v * wk1 + h3 * wk2;
    }
  }
  const int ob = kc << 8;
  h2p[(ob + t0 + fb + 0) * CCH + c] = a0;
  h2p[(ob + t0 + fb + 1) * CCH + c] = a1;
}

// ---- K3: conv3 split-K x4 (sums conv2 partials + bias2 + relu in staging) ----
__global__ __launch_bounds__(512) void conv3_k(const float* __restrict__ h2p, const float* __restrict__ w3t,
                                               const float* __restrict__ b2, float* __restrict__ ccp) {
  __shared__ float4 hs4[6 * 16];
  const int b = blockIdx.x, tid = threadIdx.x;
  const int g = b >> 2, kc = b & 3, t0 = g << 2;
  const float4* h2p4 = (const float4*)h2p;  // [p*256+t][64]
  const float4* b24 = (const float4*)b2;
  if (tid < 96) {
    int r = tid >> 4, cg = tid & 15;
    int tt = t0 - 1 + r;
    float4 s = make_float4(0.f, 0.f, 0.f, 0.f);
    if (tt >= 0 && tt < T_FRAMES) {
      s = b24[(kc << 4) + cg];
      #pragma unroll
      for (int p = 0; p < 4; ++p) {
        float4 v = h2p4[((p << 8) + tt) * 64 + (kc << 4) + cg];
        s.x += v.x; s.y += v.y; s.z += v.z; s.w += v.w;
      }
      s.x = fmaxf(s.x, 0.f); s.y = fmaxf(s.y, 0.f); s.z = fmaxf(s.z, 0.f); s.w = fmaxf(s.w, 0.f);
    }
    hs4[tid] = s;
  }
  __syncthreads();
  const int fb = (tid >> 8) << 1, c = tid & 255;
  if (c < CCEP) {
    float a0 = 0.f, a1 = 0.f;
    for (int cg = 0; cg < 16; ++cg) {
      float4 hr0 = hs4[(fb + 0) * 16 + cg];
      float4 hr1 = hs4[(fb + 1) * 16 + cg];
      float4 hr2 = hs4[(fb + 2) * 16 + cg];
      float4 hr3 = hs4[(fb + 3) * 16 + cg];
      #pragma unroll
      for (int ci = 0; ci < 4; ++ci) {
        int cin = (kc << 6) + cg * 4 + ci;
        float h0 = ((const float*)&hr0)[ci];
        float h1v = ((const float*)&hr1)[ci];
        float h2v = ((const float*)&hr2)[ci];
        float h3 = ((const float*)&hr3)[ci];
        float wk0 = w3t[(cin * 3 + 0) * CCEP + c];
        float wk1 = w3t[(cin * 3 + 1) * CCEP + c];
        float wk2 = w3t[(cin * 3 + 2) * CCEP + c];
        a0 += h0 * wk0 + h1v * wk1 + h2v * wk2;
        a1 += h1v * wk0 + h2v * wk1 + h3 * wk2;
      }
    }
    const int ob = kc << 8;
    ccp[(ob + t0 + fb + 0) * CCEP + c] = a0;
    ccp[(ob + t0 + fb + 1) * CCEP + c] = a1;
  }
}

// ---- K4: fused spectral kernel (correlation theorem, one fwd + one inv FFT) ----
__global__ __launch_bounds__(512) void fftltv_k(const float* __restrict__ ccp, const float* __restrict__ b3,
                                                const float* __restrict__ quef, const float* __restrict__ z,
                                                const float* __restrict__ win, float* __restrict__ outw) {
  __shared__ float2 U[FFT_N];
  int t = blockIdx.x, tid = threadIdx.x;
  for (int i = tid; i < FFT_N; i += 512) {
    unsigned q = br10((unsigned)i);
    float a = 0.f, bv = 0.f;
    if (q >= 401u && q < 623u) {
      int cq = (int)(q - 401u);
      int base = t * CCEP + cq;
      a = (b3[cq] + ccp[base] + ccp[256 * CCEP + base] + ccp[512 * CCEP + base] + ccp[768 * CCEP + base]) / quef[cq];
    }
    if (q < 512u) {
      int idx = t * HOP + (int)q - 255;
      bv = (idx >= 0 && idx < ZLEN) ? z[idx] : 0.f;
    }
    U[i] = make_float2(a, bv);
  }
  __syncthreads();
  #pragma unroll
  for (int s = 1; s <= 10; ++s) {
    int half = 1 << (s - 1);
    int pos = tid & (half - 1);
    int i1 = ((tid >> (s - 1)) << s) + pos;
    int i2 = i1 + half;
    float ang = (-6.283185307179586f / (float)(1 << s)) * (float)pos;
    float sn, cs; __sincosf(ang, &sn, &cs);
    float2 v2 = U[i2], v1 = U[i1];
    float tr = cs * v2.x - sn * v2.y;
    float ti = cs * v2.y + sn * v2.x;
    U[i1] = make_float2(v1.x + tr, v1.y + ti);
    U[i2] = make_float2(v1.x - tr, v1.y - ti);
    __syncthreads();
  }
  {
    int j = tid;
    int mj = (FFT_N - j) & (FFT_N - 1);
    float2 Uj = U[j], Um = U[mj];
    float2 U5j = make_float2(0.f, 0.f);
    if (tid == 0) U5j = U[512];
    auto pcalc = [](float2 Uj, float2 Um) -> float2 {
      float Ar = 0.5f * (Uj.x + Um.x);
      float Ai = 0.5f * (Uj.y - Um.y);
      float Bx = 0.5f * (Uj.y + Um.y);
      float By = 0.5f * (Um.x - Uj.x);
      float mag = __expf(0.23025850929940457f * Ar);
      float sn, cs; __sincosf(Ai, &sn, &cs);
      float SPx = mag * cs, SPy = mag * sn;
      return make_float2(Bx * SPx + By * SPy, Bx * SPy - By * SPx);
    };
    float2 Pj = pcalc(Uj, Um);
    float2 P5 = (tid == 0) ? pcalc(U5j, U5j) : make_float2(0.f, 0.f);
    __syncthreads();
    U[j] = Pj;
    if (tid == 0) U[512] = P5;
    else U[mj] = make_float2(Pj.x, -Pj.y);
  }
  __syncthreads();
  #pragma unroll
  for (int s = 10; s >= 1; --s) {
    int half = 1 << (s - 1);
    int pos = tid & (half - 1);
    int i1 = ((tid >> (s - 1)) << s) + pos;
    int i2 = i1 + half;
    float ang = (6.283185307179586f / (float)(1 << s)) * (float)pos;
    float sn, cs; __sincosf(ang, &sn, &cs);
    float2 v1 = U[i1], v2 = U[i2];
    U[i1] = make_float2(v1.x + v2.x, v1.y + v2.y);
    float dr = v1.x - v2.x, di = v1.y - v2.y;
    U[i2] = make_float2(cs * dr - sn * di, cs * di + sn * dr);
    __syncthreads();
  }
  const float inv = 1.0f / (float)FFT_N;
  for (int i = tid; i < FFT_N; i += 512) {
    unsigned m = br10((unsigned)i);
    if (m < 512u) {
      int w = 511 - (int)m;
      outw[t * WINL + w] = U[i].x * inv * win[w];
    }
  }
}

// ---- K5: overlap-add (circular roll over t) + 128-tap postfilter ----
__global__ __launch_bounds__(256) void pf_k(const float* __restrict__ outw, const float* __restrict__ pf_w,
                                            const float* __restrict__ pf_b, float* __restrict__ y) {
  __shared__ float sb[256 + PF_KT - 1];
  __shared__ float wpf[PF_KT];
  int n0 = blockIdx.x * 256;
  for (int i = threadIdx.x; i < 256 + PF_KT - 1; i += 256) {
    int m = n0 - 63 + i;
    float v = 0.f;
    if (m >= 0 && m < ZLEN) {
      int t = m >> 8, j = m & 255;
      v = outw[t * WINL + j] + outw[((t - 1) & 255) * WINL + HOP + j];
    }
    sb[i] = v;
  }
  if (threadIdx.x < PF_KT) wpf[threadIdx.x] = pf_w[threadIdx.x];
  __syncthreads();
  float acc = pf_b[0];
  #pragma unroll 8
  for (int j = 0; j < PF_KT; ++j) acc += sb[threadIdx.x + j] * wpf[j];
  y[n0 + threadIdx.x] = acc;
}

extern "C" void kernel_launch(void* const* d_in, const int* in_sizes, int n_in,
                              void* d_out, int out_size, void* d_ws, size_t ws_size,
                              hipStream_t stream) {
  const float* x    = (const float*)d_in[0];
  const float* z    = (const float*)d_in[1];
  const float* w1   = (const float*)d_in[2];
  const float* b1   = (const float*)d_in[3];
  const float* w2   = (const float*)d_in[4];
  const float* b2   = (const float*)d_in[5];
  const float* w3   = (const float*)d_in[6];
  const float* b3   = (const float*)d_in[7];
  const float* pf_w = (const float*)d_in[8];
  const float* pf_b = (const float*)d_in[9];
  const float* quef = (const float*)d_in[10];
  const float* win  = (const float*)d_in[11];
  float* out = (float*)d_out;
  float* ws  = (float*)d_ws;

  // workspace layout (floats)
  float* w1t  = ws;                 // 240*256   = 61440
  float* w2t  = w1t + 61440;        // 768*256   = 196608
  float* w3t  = w2t + 196608;       // 768*222   = 170496
  float* h1   = w3t + 170496;       // 256*256   = 65536
  float* h2p  = h1 + 65536;         // 4*256*256 = 262144
  float* ccp  = h2p + 262144;       // 4*256*222 = 227328
  float* outw = ccp + 227328;       // 256*512   = 131072

  transpose_k<<<256, 256, 0, stream>>>(w1, w2, w3, w1t, w2t, w3t);
  conv1_k<<<128, 512, 0, stream>>>(x, w1t, b1, h1);
  conv2_k<<<256, 512, 0, stream>>>(h1, w2t, h2p);
  conv3_k<<<256, 512, 0, stream>>>(h2p, w3t, b2, ccp);
  fftltv_k<<<T_FRAMES, 512, 0, stream>>>(ccp, b3, quef, z, win, outw);
  pf_k<<<ZLEN / 256, 256, 0, stream>>>(outw, pf_w, pf_b, out);
}